// Round 11
// baseline (273.500 us; speedup 1.0000x reference)
//
#include <hip/hip_runtime.h>

#define DEV static __device__ __forceinline__

typedef __attribute__((ext_vector_type(8))) short bf16x8;
typedef __attribute__((ext_vector_type(4))) float f32x4;

#define MFMA(a, b, c) __builtin_amdgcn_mfma_f32_16x16x32_bf16(a, b, c, 0, 0, 0)

DEV float bf2f(unsigned short h) { return __uint_as_float(((unsigned)h) << 16); }
DEV unsigned short f2bf(float f) {
  unsigned u = __float_as_uint(f);
  u += 0x7fffu + ((u >> 16) & 1u);
  return (unsigned short)(u >> 16);
}
DEV bf16x8 ld8(const unsigned short* p) { return *(const bf16x8*)p; }

DEV float dotg64(const float* x, const float* wrow) {
  const float4* wp = (const float4*)wrow;
  float a0 = 0.f, a1 = 0.f;
  #pragma unroll
  for (int c = 0; c < 8; ++c) {
    float4 u = wp[2*c], v = wp[2*c + 1];
    a0 = fmaf(u.x, x[8*c+0], a0); a0 = fmaf(u.y, x[8*c+1], a0);
    a0 = fmaf(u.z, x[8*c+2], a0); a0 = fmaf(u.w, x[8*c+3], a0);
    a1 = fmaf(v.x, x[8*c+4], a1); a1 = fmaf(v.y, x[8*c+5], a1);
    a1 = fmaf(v.z, x[8*c+6], a1); a1 = fmaf(v.w, x[8*c+7], a1);
  }
  return a0 + a1;
}
DEV float wred64(float v) {
  #pragma unroll
  for (int o = 32; o > 0; o >>= 1) v += __shfl_xor(v, o, 64);
  return v;
}

// d_ws layout (ushort element offsets): weights as bf16 hi/lo pairs.
// Fused composites: C0 = mW0@oW0, C1 = mW1@oW1, S = mW0+mW1 (hi/lo each),
// b' = mb + mW0@ob0 + mW1@ob1.
#define XW_HI 0        // 4*2*128*64 = 65536
#define XW_LO 65536
#define CW 131072      // per layer 24576: C0H,C0L,C1H,C1L,SH,SL (each 4096)
#define AI_HI 262144
#define AI_LO 274432
#define SC_OFF 286720  // f32: 8*256 gate-poly coefs
#define BP_OFF 290816  // f32: 4*64 fused bias b'

// bf16 tiles: 160 rows x 64 cols, stride 64, XOR swizzle:
// elem(row,d) = (row<<6) + (d ^ ((row&7)<<3)). 160 = 10x16 exact MFMA tiles.

__global__ void prep_kernel(const float* __restrict__ xW, const float* __restrict__ oW,
                            const float* __restrict__ ob, const float* __restrict__ mW,
                            const float* __restrict__ mb, const float* __restrict__ aiW,
                            const float* __restrict__ Ap, unsigned short* __restrict__ wsb) {
  const int gid = blockIdx.x * blockDim.x + threadIdx.x;
  const int stride = gridDim.x * blockDim.x;
  for (int i = gid; i < 65536; i += stride) {
    float x = xW[i]; unsigned short h = f2bf(x);
    wsb[XW_HI + i] = h; wsb[XW_LO + i] = f2bf(x - bf2f(h));
  }
  // composites C_dir[L][n][d] = sum_j mW[L][n][dir*64+j] * oW[L][dir][j][d]
  for (int i = gid; i < 32768; i += stride) {
    int L = i >> 13, rem = i & 8191;
    int dir = rem >> 12, n = (rem >> 6) & 63, d = rem & 63;
    const float* mrow = mW + L*8192 + n*128 + dir*64;
    const float* ocol = oW + L*8192 + dir*4096 + d;
    float acc = 0.f;
    #pragma unroll 8
    for (int j = 0; j < 64; ++j) acc = fmaf(mrow[j], ocol[j*64], acc);
    unsigned short h = f2bf(acc);
    int base = CW + L*24576 + dir*8192;
    wsb[base + n*64 + d] = h;
    wsb[base + 4096 + n*64 + d] = f2bf(acc - bf2f(h));
  }
  // S[L][n][j] = mW[L][n][j] + mW[L][n][64+j]
  for (int i = gid; i < 16384; i += stride) {
    int L = i >> 12, n = (i >> 6) & 63, j = i & 63;
    float v = mW[L*8192 + n*128 + j] + mW[L*8192 + n*128 + 64 + j];
    unsigned short h = f2bf(v);
    int base = CW + L*24576 + 16384;
    wsb[base + n*64 + j] = h;
    wsb[base + 4096 + n*64 + j] = f2bf(v - bf2f(h));
  }
  // b'[L][n] = mb[L][n] + sum_j ob0[j] mW[L][n][j] + sum_j ob1[j] mW[L][n][64+j]
  {
    float* bp = (float*)(wsb + BP_OFF);
    for (int i = gid; i < 256; i += stride) {
      int L = i >> 6, n = i & 63;
      const float* mrow = mW + L*8192 + n*128;
      float acc = mb[L*64 + n];
      #pragma unroll 8
      for (int j = 0; j < 64; ++j) acc = fmaf(ob[(2*L)*64 + j], mrow[j], acc);
      #pragma unroll 8
      for (int j = 0; j < 64; ++j) acc = fmaf(ob[(2*L+1)*64 + j], mrow[64 + j], acc);
      bp[i] = acc;
    }
  }
  for (int i = gid; i < 12288; i += stride) {
    float x = aiW[i]; unsigned short h = f2bf(x);
    wsb[AI_HI + i] = h; wsb[AI_LO + i] = f2bf(x - bf2f(h));
  }
  float* sc = (float*)(wsb + SC_OFF);
  for (int i = gid; i < 512; i += stride) {
    int pi = i >> 6, d = i & 63;
    const float* a = Ap + (size_t)i * 16;
    float s1 = 0, s2 = 0, s3 = 0, s4 = 0;
    #pragma unroll
    for (int n = 0; n < 16; ++n) {
      float z = a[n]; float z2 = z * z;
      s1 += z; s2 += z2; s3 += z2 * z; s4 += z2 * z2;
    }
    sc[pi*256 + d]       = s1;
    sc[pi*256 + 64 + d]  = s2 * 0.5f;
    sc[pi*256 + 128 + d] = s3 * (1.f/6.f);
    sc[pi*256 + 192 + d] = s4 * (1.f/24.f);
  }
}

// R11 = R9 structure (unroll 1, fusion, in-scan residual) with the ONE
// untested axis changed: SIMD-level TLP. 768 threads (12 waves = 3/SIMD)
// instead of 512 (2/SIMD). R10 A/B killed compiler-forced ILP (unroll 2:
// +16% wall, no spill); R9 killed work-removal (flat). At 2 waves/SIMD a
// ~120cyc ds_read stall has one covering wave; 3/SIMD gives two, AND the
// re-spread shortens the longest phase 10 -> 7 mt units per wave.
// Budget at (768,3) = 170 regs -- the budget class where R4 compiled clean
// (84 regs), avoiding the (budget-128 -> pin-64 -> spill) mode of R2/R3.
// Same LDS 145,408 -> still 1 block/CU, grid 256 = single generation.
// xproj: 80 (ct,mt) units, wave w takes contiguous [w*80/12,(w+1)*80/12)
// (max 7, <=2 wave-uniform weight reloads). fused: 40 units, [w*40/12,...)
// (max 4). LN strides 12. scan keeps 512 threads (waves 8-11 idle 1 phase).
__global__ __launch_bounds__(768, 3)
void Mamba4CTRV14_kernel(
    const float* __restrict__ dense_x, const float* __restrict__ dense_W,
    const float* __restrict__ dense_b, const float* __restrict__ tbl,
    const float* __restrict__ cls, const float* __restrict__ ng,
    const float* __restrict__ nb, const float* __restrict__ xb,
    const float* __restrict__ Dp, const float* __restrict__ ob,
    const float* __restrict__ mb, const float* __restrict__ aib,
    const float* __restrict__ aoW, const float* __restrict__ aob,
    const float* __restrict__ w1, const float* __restrict__ b1,
    const float* __restrict__ w2, const float* __restrict__ b2,
    const float* __restrict__ w3, const float* __restrict__ b3,
    const int* __restrict__ sidx, const unsigned short* __restrict__ wsb,
    float* __restrict__ out) {
  __shared__ __align__(16) unsigned char smem[145408];
  float*          s_seq  = (float*)smem;                      // 160x64 f32 spine (40960)
  unsigned short* s_xnb  = (unsigned short*)(smem + 40960);   // 160x64 bf16 xn / final seq (20480)
  unsigned short* bG0    = (unsigned short*)(smem + 61440);   // gate0->scanout0 ; tail f32 g0f
  unsigned short* bG1    = (unsigned short*)(smem + 81920);   // gate1->scanout1 ; tail f32 g1f
  unsigned short* bB0    = (unsigned short*)(smem + 102400);  // Bm0 -> residual bf16 (in-scan) ; tail: K
  unsigned short* bB1    = (unsigned short*)(smem + 122880);  // Bm1 ; tail: V
  float*          s_small= (float*)(smem + 143360);           // 512 f32: phase0 scratch
  float* g0f = (float*)bG0;          // tail: per-row 720 f32 {probs320, q64, seq0_64, c64} x4
  float* g1f = (float*)bG1;          // tail: per-row 512 f32 {aopart256, ao64, mlp1_128, mlp2_64} x4
  const float* scf = (const float*)(wsb + SC_OFF);
  const float* bpf = (const float*)(wsb + BP_OFF);

  const int tid = threadIdx.x, b = blockIdx.x;
  const int lane = tid & 63, wv = tid >> 6;  // wv 0..11
  const int arow = lane & 15;
  const int aq = (lane >> 4) * 8;
  const int rq = (lane >> 4) * 4;
  const int rq7 = rq & 7;
  const int swA = (arow & 7) << 3;
  const int aqs0 = aq ^ swA, aqs1 = (aq + 32) ^ swA;

  // ---------------- Phase 0: build seq for 4 rows ----------------
  {
    float* s_dx = s_small;               // 64 f32: br*16+k (k<13)
    int* s_idx = (int*)(s_small + 64);   // 104 ints
    if (tid < 64) {
      int br = tid >> 4, k = tid & 15;
      if (k < 13) s_dx[tid] = dense_x[(b*4 + br)*13 + k];
    }
    if (tid >= 64 && tid < 168) {
      int s = tid - 64, br = s / 26, si = s - br*26;
      int v = sidx[(b*4 + br)*26 + si];
      v = v < 0 ? 0 : (v > 10000 ? 10000 : v);
      s_idx[s] = v;
    }
    __syncthreads();
    if (tid < 256) s_seq[(tid >> 6)*40*64 + (tid & 63)] = cls[tid & 63];
    if (tid < 512) {
      const int br = tid >> 7, j0 = tid & 127;
      float x[13];
      #pragma unroll
      for (int k = 0; k < 13; ++k) x[k] = s_dx[br*16 + k];
      for (int j = j0; j < 832; j += 128) {
        float acc = dense_b[j];
        #pragma unroll
        for (int k = 0; k < 13; ++k) acc = fmaf(x[k], dense_W[j*13 + k], acc);
        s_seq[(br*40 + 1 + (j >> 6))*64 + (j & 63)] = acc;
      }
    }
    for (int e = tid; e < 1664; e += 768) {
      int br = e / 416, rem = e - br*416, s = rem >> 4, c = rem & 15;
      const float4* row = (const float4*)(tbl + ((size_t)(s*10001 + s_idx[br*26 + s]))*64);
      ((float4*)&s_seq[(br*40 + 14 + s)*64])[c] = row[c];
    }
  }
  __syncthreads();

  // ---------------- 4 bidirectional mamba layers ----------------
  for (int L = 0; L < 4; ++L) {
    const int pi0 = 2*L, pi1 = 2*L + 1;

    // LN: 80 token-pairs over 12 waves (stride 12)
    {
      const int half = lane >> 5, dl = lane & 31;
      const float ngv0 = ng[pi0*64 + dl], ngv1 = ng[pi0*64 + dl + 32];
      const float nbv0 = nb[pi0*64 + dl], nbv1 = nb[pi0*64 + dl + 32];
      #pragma unroll 1
      for (int p = wv; p < 80; p += 12) {
        int t = p*2 + half;  // 0..159
        int e = t*64 + dl;
        float x0 = s_seq[e], x1 = s_seq[e + 32];
        float s = x0 + x1, q = fmaf(x0, x0, x1*x1);
        #pragma unroll
        for (int o = 16; o > 0; o >>= 1) { s += __shfl_xor(s, o, 64); q += __shfl_xor(q, o, 64); }
        float mean = s * (1.f/64.f);
        float var = q * (1.f/64.f) - mean*mean;
        float rs = rsqrtf(var + 1e-5f);
        float xn0 = fmaf((x0 - mean) * rs, ngv0, nbv0);
        float xn1 = fmaf((x1 - mean) * rs, ngv1, nbv1);
        int sw = (t & 7) << 3;
        int eb = t << 6;
        s_xnb[eb + (dl ^ sw)] = f2bf(xn0);
        s_xnb[eb + ((dl + 32) ^ sw)] = f2bf(xn1);
      }
    }
    __syncthreads();

    // xproj both dirs fused: 80 units (ct 0..7 x mt 0..9), contiguous split
    // over 12 waves; weight frags reloaded on (wave-uniform) ct change.
    {
      const int u0 = (wv*80)/12, u1 = ((wv+1)*80)/12;
      int curct = -1;
      bf16x8 bh00, bh01, bl00, bl01, bh10, bh11, bl10, bl11;
      float bj0 = 0.f, bj1 = 0.f;
      float c10=0,c20=0,c30=0,c40=0,c11=0,c21=0,c31=0,c41=0;
      bool isDelta = false;
      int j = arow;
      #pragma unroll 1
      for (int u = u0; u < u1; ++u) {
        const int ct = u/10, mt = u - ct*10;
        if (ct != curct) {
          curct = ct;
          j = ct*16 + arow;  // 0..127
          const unsigned short* Wh0 = wsb + XW_HI + pi0*8192 + j*64;
          const unsigned short* Wl0 = wsb + XW_LO + pi0*8192 + j*64;
          const unsigned short* Wh1 = wsb + XW_HI + pi1*8192 + j*64;
          const unsigned short* Wl1 = wsb + XW_LO + pi1*8192 + j*64;
          bh00 = ld8(Wh0 + aq); bh01 = ld8(Wh0 + 32 + aq);
          bl00 = ld8(Wl0 + aq); bl01 = ld8(Wl0 + 32 + aq);
          bh10 = ld8(Wh1 + aq); bh11 = ld8(Wh1 + 32 + aq);
          bl10 = ld8(Wl1 + aq); bl11 = ld8(Wl1 + 32 + aq);
          bj0 = xb[pi0*128 + j]; bj1 = xb[pi1*128 + j];
          isDelta = (ct < 4);
          if (isDelta) {
            c10=scf[pi0*256+j]; c20=scf[pi0*256+64+j]; c30=scf[pi0*256+128+j]; c40=scf[pi0*256+192+j];
            c11=scf[pi1*256+j]; c21=scf[pi1*256+64+j]; c31=scf[pi1*256+128+j]; c41=scf[pi1*256+192+j];
          }
        }
        const unsigned short* A = s_xnb + ((mt*16 + arow) << 6);
        bf16x8 ah0 = ld8(A + aqs0), ah1 = ld8(A + aqs1);
        f32x4 a0 = {0,0,0,0}, a1 = {0,0,0,0};
        a0 = MFMA(ah0, bh00, a0); a0 = MFMA(ah0, bl00, a0);
        a0 = MFMA(ah1, bh01, a0); a0 = MFMA(ah1, bl01, a0);
        a1 = MFMA(ah0, bh10, a1); a1 = MFMA(ah0, bl10, a1);
        a1 = MFMA(ah1, bh11, a1); a1 = MFMA(ah1, bl11, a1);
        const int rbase = mt*16 + rq;
        #pragma unroll
        for (int r = 0; r < 4; ++r) {
          int row = rbase + r;  // 0..159 exact
          int swr = (rq7 + r) << 3;
          float x0v = a0[r] + bj0, x1v = a1[r] + bj1;
          if (isDelta) {
            float sp0 = fmaxf(x0v, 0.f) + __logf(1.f + __expf(-fabsf(x0v)));
            float sp1 = fmaxf(x1v, 0.f) + __logf(1.f + __expf(-fabsf(x1v)));
            int o = (row << 6) + (j ^ swr);
            bG0[o] = f2bf(sp0 * fmaf(sp0, fmaf(sp0, fmaf(sp0, c40, c30), c20), c10));
            bG1[o] = f2bf(sp1 * fmaf(sp1, fmaf(sp1, fmaf(sp1, c41, c31), c21), c11));
          } else {
            int o = (row << 6) + ((j - 64) ^ swr);
            bB0[o] = f2bf(x0v);
            bB1[o] = f2bf(x1v);
          }
        }
      }
    }
    __syncthreads();

    // Scan: single pass, 512 streams (br,dir,d) on threads 0..511, 40 steps.
    // dir-0 threads overwrite consumed Bm0 with the bf16 residual (s_seq),
    // building the swizzled residual tile for the fused phase for free.
    if (tid < 512) {
      const int d = tid & 63, dir = (tid >> 6) & 1, br = tid >> 7;  // br 0..3
      unsigned short* bmb = dir ? bB1 : bB0;
      unsigned short* gb = dir ? bG1 : bG0;
      const float dpd = Dp[(pi0 + dir)*64 + d];
      const int base = br*40;
      float run = 0.f;
      #pragma unroll
      for (int k = 0; k < 40; ++k) {
        int t = base + (dir ? (39 - k) : k);
        int o = (t << 6) + (d ^ ((t & 7) << 3));
        float xn = bf2f(s_xnb[o]);
        run = fmaf(xn, bf2f(bmb[o]), run);
        float gate = 16.f + bf2f(gb[o]);
        gb[o] = f2bf(fmaf(run, gate, xn * dpd));
        if (dir == 0) bmb[o] = f2bf(s_seq[t*64 + d]);  // wave-uniform branch
      }
    }
    __syncthreads();

    // FUSED out+merge: seq_new = g0@C0^T + g1@C1^T + res@S^T + b'
    // (res tile = bB0). 40 units (ct 0..3 x mt 0..9) contiguous over 12 waves.
    {
      const int u0 = (wv*40)/12, u1 = ((wv+1)*40)/12;
      int curct = -1;
      bf16x8 c0h0, c0h1, c0l0, c0l1, c1h0, c1h1, c1l0, c1l1, sh0, sh1, sl0, sl1;
      float bom = 0.f;
      int n0 = arow;
      #pragma unroll 1
      for (int u = u0; u < u1; ++u) {
        const int ct = u/10, mt = u - ct*10;
        if (ct != curct) {
          curct = ct;
          n0 = ct*16 + arow;  // 0..63
          const unsigned short* cbase = wsb + CW + L*24576;
          const unsigned short* C0H = cbase + n0*64;
          const unsigned short* C0L = cbase + 4096 + n0*64;
          const unsigned short* C1H = cbase + 8192 + n0*64;
          const unsigned short* C1L = cbase + 12288 + n0*64;
          const unsigned short* SH  = cbase + 16384 + n0*64;
          const unsigned short* SL  = cbase + 20480 + n0*64;
          c0h0 = ld8(C0H + aq); c0h1 = ld8(C0H + 32 + aq);
          c0l0 = ld8(C0L + aq); c0l1 = ld8(C0L + 32 + aq);
          c1h0 = ld8(C1H + aq); c1h1 = ld8(C1H + 32 + aq);
          c1l0 = ld8(C1L + aq); c1l1 = ld8(C1L + 32 + aq);
          sh0 = ld8(SH + aq); sh1 = ld8(SH + 32 + aq);
          sl0 = ld8(SL + aq); sl1 = ld8(SL + 32 + aq);
          bom = bpf[L*64 + n0];
        }
        const unsigned short* A0 = bG0 + ((mt*16 + arow) << 6);
        const unsigned short* A1 = bG1 + ((mt*16 + arow) << 6);
        const unsigned short* AR = bB0 + ((mt*16 + arow) << 6);
        bf16x8 g00 = ld8(A0 + aqs0), g01 = ld8(A0 + aqs1);
        bf16x8 g10 = ld8(A1 + aqs0), g11 = ld8(A1 + aqs1);
        bf16x8 r0 = ld8(AR + aqs0), r1 = ld8(AR + aqs1);
        f32x4 a0 = {0,0,0,0}, a1 = {0,0,0,0}, a2 = {0,0,0,0};
        a0 = MFMA(g00, c0h0, a0); a0 = MFMA(g00, c0l0, a0);
        a0 = MFMA(g01, c0h1, a0); a0 = MFMA(g01, c0l1, a0);
        a1 = MFMA(g10, c1h0, a1); a1 = MFMA(g10, c1l0, a1);
        a1 = MFMA(g11, c1h1, a1); a1 = MFMA(g11, c1l1, a1);
        a2 = MFMA(r0, sh0, a2); a2 = MFMA(r0, sl0, a2);
        a2 = MFMA(r1, sh1, a2); a2 = MFMA(r1, sl1, a2);
        const int rbase = mt*16 + rq;
        #pragma unroll
        for (int r = 0; r < 4; ++r) {
          int row = rbase + r;
          float v = a0[r] + a1[r] + a2[r] + bom;
          s_seq[row*64 + n0] = v;
          if (L == 3) s_xnb[(row << 6) + (n0 ^ ((rq7 + r) << 3))] = f2bf(v);
        }
      }
    }
    __syncthreads();
  }

  // ---------------- Attention tail ----------------
  // QKV: 96 units (K/V: 8 ct x 10 mt = 80; Q: 4 ct x 4 mt{0,2,5,7} = 16)
  // over 12 waves = 8 each (wv + 12*i, i<8: max u = 11+84 = 95)
  {
    #pragma unroll 1
    for (int i = 0; i < 8; ++i) {
      const int u = wv + 12*i;  // 0..95
      int j, mtk;
      if (u < 80) { j = 64 + (u & 7)*16 + arow; mtk = u >> 3; }
      else {
        int qi = u - 80;                 // 0..15
        j = (qi & 3)*16 + arow;
        int p = qi >> 2;                 // 0..3
        mtk = p*2 + (p >> 1);            // {0,2,5,7}
      }
      const unsigned short* Wh = wsb + AI_HI + j*64;
      const unsigned short* Wl = wsb + AI_LO + j*64;
      bf16x8 bh0 = ld8(Wh + aq), bh1 = ld8(Wh + 32 + aq);
      bf16x8 bl0 = ld8(Wl + aq), bl1 = ld8(Wl + 32 + aq);
      const float bj = aib[j];
      const unsigned short* A = s_xnb + ((mtk*16 + arow) << 6);
      bf16x8 ah0 = ld8(A + aqs0), ah1 = ld8(A + aqs1);
      f32x4 a0 = {0,0,0,0};
      a0 = MFMA(ah0, bh0, a0); a0 = MFMA(ah0, bl0, a0);
      a0 = MFMA(ah1, bh1, a0); a0 = MFMA(ah1, bl1, a0);
      const int rbase = mtk*16 + rq;
      #pragma unroll
      for (int r = 0; r < 4; ++r) {
        int row = rbase + r;
        int swr = (rq7 + r) << 3;
        float val = a0[r] + bj;
        if (u < 80) {
          if (j < 128) bB0[(row << 6) + ((j - 64) ^ swr)] = f2bf(val);   // K
          else         bB1[(row << 6) + ((j - 128) ^ swr)] = f2bf(val);  // V
        } else {
          if (row % 40 == 0) g0f[(row/40)*720 + 320 + j] = val;          // q per batch-row
        }
      }
    }
    if (tid < 256) g0f[(tid >> 6)*720 + 384 + (tid & 63)] = s_seq[(tid >> 6)*40*64 + (tid & 63)];
  }
  __syncthreads();

  // logits: 4 rows x 8 heads x 40 keys = 1280
  for (int e = tid; e < 1280; e += 768) {
    int br = e / 320, rem = e - br*320;
    int h = rem / 40, kk = rem - h*40;
    int row = br*40 + kk;
    int kbase = (row << 6) + ((h*8) ^ ((kk & 7) << 3));
    float acc = 0.f;
    #pragma unroll
    for (int i = 0; i < 8; ++i)
      acc += g0f[br*720 + 320 + h*8 + i] * bf2f(bB0[kbase + i]);
    g0f[br*720 + rem] = acc * 0.35355339059327373f;
  }
  __syncthreads();

  // softmax: 32 heads over waves 0..7, 16 lanes per head (40 keys = 16+16+8)
  if (wv < 8) {
    const int hh = wv*4 + (lane >> 4), jl = lane & 15;
    float* pr = g0f + (hh >> 3)*720 + (hh & 7)*40;
    float a = pr[jl];
    float bv = pr[16 + jl];
    float cv = (jl < 8) ? pr[32 + jl] : -1e30f;
    float m = fmaxf(fmaxf(a, bv), cv);
    #pragma unroll
    for (int o = 8; o > 0; o >>= 1) m = fmaxf(m, __shfl_xor(m, o, 16));
    float pa = __expf(a - m), pb = __expf(bv - m), pc = (jl < 8) ? __expf(cv - m) : 0.f;
    float s = pa + pb + pc;
    #pragma unroll
    for (int o = 8; o > 0; o >>= 1) s += __shfl_xor(s, o, 16);
    float inv = 1.f / s;
    pr[jl] = pa * inv;
    pr[16 + jl] = pb * inv;
    if (jl < 8) pr[32 + jl] = pc * inv;
  }
  __syncthreads();

  // ao partials: 4 rows x 4 quarters x 64 d = 1024
  for (int e = tid; e < 1024; e += 768) {
    const int d = e & 63, qrt = (e >> 6) & 3, br = e >> 8, hh = d >> 3;
    float acc = 0.f;
    #pragma unroll
    for (int k = qrt*10; k < qrt*10 + 10; ++k) {
      int o = ((br*40 + k) << 6) + (d ^ ((k & 7) << 3));
      acc += g0f[br*720 + hh*40 + k] * bf2f(bB1[o]);
    }
    g1f[br*512 + qrt*64 + d] = acc;
  }
  __syncthreads();
  if (tid < 256) {
    float* p = g1f + (tid >> 6)*512;
    int d = tid & 63;
    p[256 + d] = p[d] + p[64 + d] + p[128 + d] + p[192 + d];
  }
  __syncthreads();

  // c = seq0 + ao @ aoW.T + aob
  if (tid < 256) {
    int br = tid >> 6, o = tid & 63;
    g0f[br*720 + 448 + o] = g0f[br*720 + 384 + o] + aob[o]
                          + dotg64(&g1f[br*512 + 256], aoW + (size_t)o*64);
  }
  __syncthreads();

  // MLP1: 4 rows x 128 = 512
  if (tid < 512) {
    int br = tid >> 7, o = tid & 127;
    g1f[br*512 + 320 + o] = fmaxf(b1[o] + dotg64(&g0f[br*720 + 448], w1 + (size_t)o*64), 0.f);
  }
  __syncthreads();

  // MLP2
  if (tid < 256) {
    int br = tid >> 6, o = tid & 63;
    float acc = dotg64(&g1f[br*512 + 320], w2 + (size_t)o*128)
              + dotg64(&g1f[br*512 + 384], w2 + (size_t)o*128 + 64);
    g1f[br*512 + 448 + o] = fmaxf(acc + b2[o], 0.f);
  }
  __syncthreads();

  if (tid < 256) {
    int br = tid >> 6;
    float v = g1f[br*512 + 448 + lane] * w3[lane];
    v = wred64(v);
    if (lane == 0) out[b*4 + br] = v + b3[0];
  }
}

extern "C" void kernel_launch(void* const* d_in, const int* in_sizes, int n_in,
                              void* d_out, int out_size, void* d_ws, size_t ws_size,
                              hipStream_t stream) {
  (void)n_in; (void)ws_size; (void)out_size;
  const float* dense_x = (const float*)d_in[0];
  const float* dense_W = (const float*)d_in[1];
  const float* dense_b = (const float*)d_in[2];
  const float* tbl     = (const float*)d_in[3];
  const float* cls     = (const float*)d_in[4];
  const float* ng      = (const float*)d_in[5];
  const float* nb      = (const float*)d_in[6];
  const float* xW      = (const float*)d_in[7];
  const float* xb      = (const float*)d_in[8];
  const float* Ap      = (const float*)d_in[9];
  const float* Dp      = (const float*)d_in[10];
  const float* oW      = (const float*)d_in[11];
  const float* ob      = (const float*)d_in[12];
  const float* mW      = (const float*)d_in[13];
  const float* mb      = (const float*)d_in[14];
  const float* aiW     = (const float*)d_in[15];
  const float* aib     = (const float*)d_in[16];
  const float* aoW     = (const float*)d_in[17];
  const float* aob     = (const float*)d_in[18];
  const float* w1      = (const float*)d_in[19];
  const float* b1      = (const float*)d_in[20];
  const float* w2      = (const float*)d_in[21];
  const float* b2      = (const float*)d_in[22];
  const float* w3      = (const float*)d_in[23];
  const float* b3      = (const float*)d_in[24];
  const int*   sidx    = (const int*)d_in[25];
  float* out = (float*)d_out;
  unsigned short* wsb = (unsigned short*)d_ws;

  hipLaunchKernelGGL(prep_kernel, dim3(256), dim3(256), 0, stream,
                     xW, oW, ob, mW, mb, aiW, Ap, wsb);

  const int B = in_sizes[0] / 13;  // 1024
  hipLaunchKernelGGL(Mamba4CTRV14_kernel, dim3(B/4), dim3(768), 0, stream,
                     dense_x, dense_W, dense_b, tbl, cls, ng, nb, xb, Dp, ob, mb,
                     aib, aoW, aob, w1, b1, w2, b2, w3, b3, sidx, wsb, out);
}

// Round 12
// 254.758 us; speedup vs baseline: 1.0736x; 1.0736x over previous
//
#include <hip/hip_runtime.h>

#define DEV static __device__ __forceinline__

typedef __attribute__((ext_vector_type(8))) short bf16x8;
typedef __attribute__((ext_vector_type(4))) float f32x4;

#define MFMA(a, b, c) __builtin_amdgcn_mfma_f32_16x16x32_bf16(a, b, c, 0, 0, 0)

DEV float bf2f(unsigned short h) { return __uint_as_float(((unsigned)h) << 16); }
DEV unsigned short f2bf(float f) {
  unsigned u = __float_as_uint(f);
  u += 0x7fffu + ((u >> 16) & 1u);
  return (unsigned short)(u >> 16);
}
DEV bf16x8 ld8(const unsigned short* p) { return *(const bf16x8*)p; }

DEV float dotg64(const float* x, const float* wrow) {
  const float4* wp = (const float4*)wrow;
  float a0 = 0.f, a1 = 0.f;
  #pragma unroll
  for (int c = 0; c < 8; ++c) {
    float4 u = wp[2*c], v = wp[2*c + 1];
    a0 = fmaf(u.x, x[8*c+0], a0); a0 = fmaf(u.y, x[8*c+1], a0);
    a0 = fmaf(u.z, x[8*c+2], a0); a0 = fmaf(u.w, x[8*c+3], a0);
    a1 = fmaf(v.x, x[8*c+4], a1); a1 = fmaf(v.y, x[8*c+5], a1);
    a1 = fmaf(v.z, x[8*c+6], a1); a1 = fmaf(v.w, x[8*c+7], a1);
  }
  return a0 + a1;
}
DEV float wred64(float v) {
  #pragma unroll
  for (int o = 32; o > 0; o >>= 1) v += __shfl_xor(v, o, 64);
  return v;
}

// d_ws layout (ushort element offsets): weights as bf16 hi/lo pairs.
// Fused composites: C0 = mW0@oW0, C1 = mW1@oW1, S = mW0+mW1 (hi/lo each),
// b' = mb + mW0@ob0 + mW1@ob1.
#define XW_HI 0        // 4*2*128*64 = 65536
#define XW_LO 65536
#define CW 131072      // per layer 24576: C0H,C0L,C1H,C1L,SH,SL (each 4096)
#define AI_HI 262144
#define AI_LO 274432
#define SC_OFF 286720  // f32: 8*256 gate-poly coefs
#define BP_OFF 290816  // f32: 4*64 fused bias b'

// bf16 tiles: 160 rows x 64 cols, stride 64, XOR swizzle:
// elem(row,d) = (row<<6) + (d ^ ((row&7)<<3)). 160 = 10x16 exact MFMA tiles.
// sw is a multiple of 8 -> XOR preserves adjacency within 8-elem chunks, so
// aligned u32/b64 accesses of adjacent d's stay legal post-swizzle.

__global__ void prep_kernel(const float* __restrict__ xW, const float* __restrict__ oW,
                            const float* __restrict__ ob, const float* __restrict__ mW,
                            const float* __restrict__ mb, const float* __restrict__ aiW,
                            const float* __restrict__ Ap, unsigned short* __restrict__ wsb) {
  const int gid = blockIdx.x * blockDim.x + threadIdx.x;
  const int stride = gridDim.x * blockDim.x;
  for (int i = gid; i < 65536; i += stride) {
    float x = xW[i]; unsigned short h = f2bf(x);
    wsb[XW_HI + i] = h; wsb[XW_LO + i] = f2bf(x - bf2f(h));
  }
  // composites C_dir[L][n][d] = sum_j mW[L][n][dir*64+j] * oW[L][dir][j][d]
  for (int i = gid; i < 32768; i += stride) {
    int L = i >> 13, rem = i & 8191;
    int dir = rem >> 12, n = (rem >> 6) & 63, d = rem & 63;
    const float* mrow = mW + L*8192 + n*128 + dir*64;
    const float* ocol = oW + L*8192 + dir*4096 + d;
    float acc = 0.f;
    #pragma unroll 8
    for (int j = 0; j < 64; ++j) acc = fmaf(mrow[j], ocol[j*64], acc);
    unsigned short h = f2bf(acc);
    int base = CW + L*24576 + dir*8192;
    wsb[base + n*64 + d] = h;
    wsb[base + 4096 + n*64 + d] = f2bf(acc - bf2f(h));
  }
  // S[L][n][j] = mW[L][n][j] + mW[L][n][64+j]
  for (int i = gid; i < 16384; i += stride) {
    int L = i >> 12, n = (i >> 6) & 63, j = i & 63;
    float v = mW[L*8192 + n*128 + j] + mW[L*8192 + n*128 + 64 + j];
    unsigned short h = f2bf(v);
    int base = CW + L*24576 + 16384;
    wsb[base + n*64 + j] = h;
    wsb[base + 4096 + n*64 + j] = f2bf(v - bf2f(h));
  }
  // b'[L][n] = mb[L][n] + sum_j ob0[j] mW[L][n][j] + sum_j ob1[j] mW[L][n][64+j]
  {
    float* bp = (float*)(wsb + BP_OFF);
    for (int i = gid; i < 256; i += stride) {
      int L = i >> 6, n = i & 63;
      const float* mrow = mW + L*8192 + n*128;
      float acc = mb[L*64 + n];
      #pragma unroll 8
      for (int j = 0; j < 64; ++j) acc = fmaf(ob[(2*L)*64 + j], mrow[j], acc);
      #pragma unroll 8
      for (int j = 0; j < 64; ++j) acc = fmaf(ob[(2*L+1)*64 + j], mrow[64 + j], acc);
      bp[i] = acc;
    }
  }
  for (int i = gid; i < 12288; i += stride) {
    float x = aiW[i]; unsigned short h = f2bf(x);
    wsb[AI_HI + i] = h; wsb[AI_LO + i] = f2bf(x - bf2f(h));
  }
  float* sc = (float*)(wsb + SC_OFF);
  for (int i = gid; i < 512; i += stride) {
    int pi = i >> 6, d = i & 63;
    const float* a = Ap + (size_t)i * 16;
    float s1 = 0, s2 = 0, s3 = 0, s4 = 0;
    #pragma unroll
    for (int n = 0; n < 16; ++n) {
      float z = a[n]; float z2 = z * z;
      s1 += z; s2 += z2; s3 += z2 * z; s4 += z2 * z2;
    }
    sc[pi*256 + d]       = s1;
    sc[pi*256 + 64 + d]  = s2 * 0.5f;
    sc[pi*256 + 128 + d] = s3 * (1.f/6.f);
    sc[pi*256 + 192 + d] = s4 * (1.f/24.f);
  }
}

// R12 = R9 structure with the DS-PIPE (not wave/ILP/work) attacked.
// R11 falsifier: +50% waves left VALUBusy pinned at 34% -> the stall is a
// per-CU shared resource, and the budget says it's the single LDS/DS pipe:
// ~4,300 DS-instr/layer (scan 1,920 + LN 1,120 incl. ds_bpermute shuffles +
// xproj 800 + fused 440) ~= 45-55us of the 122us wall.
// Changes vs R9 (math identical, DS-instr -40%):
//  1. Scan pairing: 1 thread per d-PAIR (256 thr, dir wave-uniform at
//     tid>=128); all tile traffic u32/b64 (adjacency survives the swizzle).
//     1,920 -> 960 DS-instr.
//  2. LN 4-wide: 1 lane = 4 adjacent d's via float4 read + b64 write; token
//     per 16-lane group (bank-rotated); reduce = 8 bpermutes per 4 tokens.
//     1,120 -> ~400 DS-instr.
// Falsifier (pre-registered): dur >= 118 + clean counters -> DS-pipe not
// binding -> barrier-serialized structure is at its floor.
__global__ __launch_bounds__(512, 2)
void Mamba4CTRV15_kernel(
    const float* __restrict__ dense_x, const float* __restrict__ dense_W,
    const float* __restrict__ dense_b, const float* __restrict__ tbl,
    const float* __restrict__ cls, const float* __restrict__ ng,
    const float* __restrict__ nb, const float* __restrict__ xb,
    const float* __restrict__ Dp, const float* __restrict__ ob,
    const float* __restrict__ mb, const float* __restrict__ aib,
    const float* __restrict__ aoW, const float* __restrict__ aob,
    const float* __restrict__ w1, const float* __restrict__ b1,
    const float* __restrict__ w2, const float* __restrict__ b2,
    const float* __restrict__ w3, const float* __restrict__ b3,
    const int* __restrict__ sidx, const unsigned short* __restrict__ wsb,
    float* __restrict__ out) {
  __shared__ __align__(16) unsigned char smem[145408];
  float*          s_seq  = (float*)smem;                      // 160x64 f32 spine (40960)
  unsigned short* s_xnb  = (unsigned short*)(smem + 40960);   // 160x64 bf16 xn / final seq (20480)
  unsigned short* bG0    = (unsigned short*)(smem + 61440);   // gate0->scanout0 ; tail f32 g0f
  unsigned short* bG1    = (unsigned short*)(smem + 81920);   // gate1->scanout1 ; tail f32 g1f
  unsigned short* bB0    = (unsigned short*)(smem + 102400);  // Bm0 -> residual bf16 (in-scan) ; tail: K
  unsigned short* bB1    = (unsigned short*)(smem + 122880);  // Bm1 ; tail: V
  float*          s_small= (float*)(smem + 143360);           // 512 f32: phase0 scratch
  float* g0f = (float*)bG0;          // tail: per-row 720 f32 {probs320, q64, seq0_64, c64} x4
  float* g1f = (float*)bG1;          // tail: per-row 512 f32 {aopart256, ao64, mlp1_128, mlp2_64} x4
  const float* scf = (const float*)(wsb + SC_OFF);
  const float* bpf = (const float*)(wsb + BP_OFF);

  const int tid = threadIdx.x, b = blockIdx.x;
  const int lane = tid & 63, wv = tid >> 6;  // wv 0..7
  const int arow = lane & 15;
  const int aq = (lane >> 4) * 8;
  const int rq = (lane >> 4) * 4;
  const int rq7 = rq & 7;
  const int swA = (arow & 7) << 3;
  const int aqs0 = aq ^ swA, aqs1 = (aq + 32) ^ swA;

  // ---------------- Phase 0: build seq for 4 rows ----------------
  {
    float* s_dx = s_small;               // 64 f32: br*16+k (k<13)
    int* s_idx = (int*)(s_small + 64);   // 104 ints
    if (tid < 64) {
      int br = tid >> 4, k = tid & 15;
      if (k < 13) s_dx[tid] = dense_x[(b*4 + br)*13 + k];
    }
    if (tid >= 64 && tid < 168) {
      int s = tid - 64, br = s / 26, si = s - br*26;
      int v = sidx[(b*4 + br)*26 + si];
      v = v < 0 ? 0 : (v > 10000 ? 10000 : v);
      s_idx[s] = v;
    }
    __syncthreads();
    if (tid < 256) s_seq[(tid >> 6)*40*64 + (tid & 63)] = cls[tid & 63];
    {
      const int br = tid >> 7, j0 = tid & 127;
      float x[13];
      #pragma unroll
      for (int k = 0; k < 13; ++k) x[k] = s_dx[br*16 + k];
      for (int j = j0; j < 832; j += 128) {
        float acc = dense_b[j];
        #pragma unroll
        for (int k = 0; k < 13; ++k) acc = fmaf(x[k], dense_W[j*13 + k], acc);
        s_seq[(br*40 + 1 + (j >> 6))*64 + (j & 63)] = acc;
      }
    }
    for (int e = tid; e < 1664; e += 512) {
      int br = e / 416, rem = e - br*416, s = rem >> 4, c = rem & 15;
      const float4* row = (const float4*)(tbl + ((size_t)(s*10001 + s_idx[br*26 + s]))*64);
      ((float4*)&s_seq[(br*40 + 14 + s)*64])[c] = row[c];
    }
  }
  __syncthreads();

  // ---------------- 4 bidirectional mamba layers ----------------
  for (int L = 0; L < 4; ++L) {
    const int pi0 = 2*L, pi1 = 2*L + 1;

    // LN 4-wide: 160 tokens = 5 sweeps x (8 waves x 4 token-groups);
    // lane = 4 adjacent d's (rotated per group to stagger banks).
    {
      const int g = lane >> 4, dl = lane & 15;
      const int dbase = 4 * ((dl + 4*g) & 15);
      const float4 ngv = *(const float4*)&ng[pi0*64 + dbase];
      const float4 nbv = *(const float4*)&nb[pi0*64 + dbase];
      #pragma unroll 1
      for (int sweep = 0; sweep < 5; ++sweep) {
        int t = sweep*32 + wv*4 + g;  // 0..159
        const float4 xv = *(const float4*)&s_seq[t*64 + dbase];
        float s = (xv.x + xv.y) + (xv.z + xv.w);
        float q = fmaf(xv.x, xv.x, fmaf(xv.y, xv.y, fmaf(xv.z, xv.z, xv.w*xv.w)));
        #pragma unroll
        for (int o = 8; o > 0; o >>= 1) { s += __shfl_xor(s, o, 64); q += __shfl_xor(q, o, 64); }
        float mean = s * (1.f/64.f);
        float var = q * (1.f/64.f) - mean*mean;
        float rs = rsqrtf(var + 1e-5f);
        unsigned short h0 = f2bf(fmaf((xv.x - mean)*rs, ngv.x, nbv.x));
        unsigned short h1 = f2bf(fmaf((xv.y - mean)*rs, ngv.y, nbv.y));
        unsigned short h2 = f2bf(fmaf((xv.z - mean)*rs, ngv.z, nbv.z));
        unsigned short h3 = f2bf(fmaf((xv.w - mean)*rs, ngv.w, nbv.w));
        int o2 = (t << 6) + (dbase ^ ((t & 7) << 3));
        unsigned lo = (unsigned)h0 | ((unsigned)h1 << 16);
        unsigned hi = (unsigned)h2 | ((unsigned)h3 << 16);
        *(uint2*)&s_xnb[o2] = make_uint2(lo, hi);
      }
    }
    __syncthreads();

    // xproj both dirs fused: wave w -> col j (delta w<4 -> bG*, Bm w>=4 -> bB*), 10 mt
    {
      const int j = wv*16 + arow;  // 0..127
      const unsigned short* Wh0 = wsb + XW_HI + pi0*8192 + j*64;
      const unsigned short* Wl0 = wsb + XW_LO + pi0*8192 + j*64;
      const unsigned short* Wh1 = wsb + XW_HI + pi1*8192 + j*64;
      const unsigned short* Wl1 = wsb + XW_LO + pi1*8192 + j*64;
      bf16x8 bh00 = ld8(Wh0 + aq), bh01 = ld8(Wh0 + 32 + aq);
      bf16x8 bl00 = ld8(Wl0 + aq), bl01 = ld8(Wl0 + 32 + aq);
      bf16x8 bh10 = ld8(Wh1 + aq), bh11 = ld8(Wh1 + 32 + aq);
      bf16x8 bl10 = ld8(Wl1 + aq), bl11 = ld8(Wl1 + 32 + aq);
      const float bj0 = xb[pi0*128 + j], bj1 = xb[pi1*128 + j];
      const bool isDelta = (wv < 4);  // wave-uniform
      float c10=0,c20=0,c30=0,c40=0,c11=0,c21=0,c31=0,c41=0;
      if (isDelta) {
        c10=scf[pi0*256+j]; c20=scf[pi0*256+64+j]; c30=scf[pi0*256+128+j]; c40=scf[pi0*256+192+j];
        c11=scf[pi1*256+j]; c21=scf[pi1*256+64+j]; c31=scf[pi1*256+128+j]; c41=scf[pi1*256+192+j];
      }
      #pragma unroll 1
      for (int mt = 0; mt < 10; ++mt) {
        const unsigned short* A = s_xnb + ((mt*16 + arow) << 6);
        bf16x8 ah0 = ld8(A + aqs0), ah1 = ld8(A + aqs1);
        f32x4 a0 = {0,0,0,0}, a1 = {0,0,0,0};
        a0 = MFMA(ah0, bh00, a0); a0 = MFMA(ah0, bl00, a0);
        a0 = MFMA(ah1, bh01, a0); a0 = MFMA(ah1, bl01, a0);
        a1 = MFMA(ah0, bh10, a1); a1 = MFMA(ah0, bl10, a1);
        a1 = MFMA(ah1, bh11, a1); a1 = MFMA(ah1, bl11, a1);
        const int rbase = mt*16 + rq;
        #pragma unroll
        for (int r = 0; r < 4; ++r) {
          int row = rbase + r;  // 0..159 exact
          int swr = (rq7 + r) << 3;
          float x0v = a0[r] + bj0, x1v = a1[r] + bj1;
          if (isDelta) {
            float sp0 = fmaxf(x0v, 0.f) + __logf(1.f + __expf(-fabsf(x0v)));
            float sp1 = fmaxf(x1v, 0.f) + __logf(1.f + __expf(-fabsf(x1v)));
            int o = (row << 6) + (j ^ swr);
            bG0[o] = f2bf(sp0 * fmaf(sp0, fmaf(sp0, fmaf(sp0, c40, c30), c20), c10));
            bG1[o] = f2bf(sp1 * fmaf(sp1, fmaf(sp1, fmaf(sp1, c41, c31), c21), c11));
          } else {
            int o = (row << 6) + ((j - 64) ^ swr);
            bB0[o] = f2bf(x0v);
            bB1[o] = f2bf(x1v);
          }
        }
      }
    }
    __syncthreads();

    // Scan (paired): 256 streams of d-pairs, 40 steps; all tile ops u32/b64.
    // tid<128 -> dir0 (waves 0,1), tid 128..255 -> dir1 (waves 2,3): dir is
    // wave-uniform, so the dir-0 residual overwrite of consumed Bm0 stays a
    // uniform branch. Each wave covers 2 br x 32 pairs.
    if (tid < 256) {
      const int d0 = (tid & 31) * 2, br = (tid >> 5) & 3, dir = tid >> 7;
      unsigned short* bmb = dir ? bB1 : bB0;
      unsigned short* gb = dir ? bG1 : bG0;
      const float2 dpd = *(const float2*)&Dp[(pi0 + dir)*64 + d0];
      const int base = br*40;
      float run0 = 0.f, run1 = 0.f;
      #pragma unroll
      for (int k = 0; k < 40; ++k) {
        int t = base + (dir ? (39 - k) : k);
        int o = (t << 6) + (d0 ^ ((t & 7) << 3));
        unsigned xn2 = *(const unsigned*)&s_xnb[o];
        unsigned bm2 = *(const unsigned*)&bmb[o];
        unsigned g2  = *(const unsigned*)&gb[o];
        float xn0 = bf2f((unsigned short)xn2), xn1 = bf2f((unsigned short)(xn2 >> 16));
        run0 = fmaf(xn0, bf2f((unsigned short)bm2), run0);
        run1 = fmaf(xn1, bf2f((unsigned short)(bm2 >> 16)), run1);
        float gate0 = 16.f + bf2f((unsigned short)g2);
        float gate1 = 16.f + bf2f((unsigned short)(g2 >> 16));
        unsigned short r0 = f2bf(fmaf(run0, gate0, xn0 * dpd.x));
        unsigned short r1 = f2bf(fmaf(run1, gate1, xn1 * dpd.y));
        *(unsigned*)&gb[o] = (unsigned)r0 | ((unsigned)r1 << 16);
        if (dir == 0) {
          float2 sv = *(const float2*)&s_seq[t*64 + d0];
          *(unsigned*)&bmb[o] = (unsigned)f2bf(sv.x) | ((unsigned)f2bf(sv.y) << 16);
        }
      }
    }
    __syncthreads();

    // FUSED out+merge: seq_new = g0@C0^T + g1@C1^T + res@S^T + b'
    // (res tile = bB0, written during scan). 3 independent 4-MFMA chains/mt.
    {
      const int n0 = (wv & 3)*16 + arow;
      const int mt0 = (wv < 4) ? 0 : 5, mt1 = (wv < 4) ? 5 : 10;
      const unsigned short* cbase = wsb + CW + L*24576;
      const unsigned short* C0H = cbase + n0*64;
      const unsigned short* C0L = cbase + 4096 + n0*64;
      const unsigned short* C1H = cbase + 8192 + n0*64;
      const unsigned short* C1L = cbase + 12288 + n0*64;
      const unsigned short* SH  = cbase + 16384 + n0*64;
      const unsigned short* SL  = cbase + 20480 + n0*64;
      bf16x8 c0h0 = ld8(C0H + aq), c0h1 = ld8(C0H + 32 + aq);
      bf16x8 c0l0 = ld8(C0L + aq), c0l1 = ld8(C0L + 32 + aq);
      bf16x8 c1h0 = ld8(C1H + aq), c1h1 = ld8(C1H + 32 + aq);
      bf16x8 c1l0 = ld8(C1L + aq), c1l1 = ld8(C1L + 32 + aq);
      bf16x8 sh0 = ld8(SH + aq), sh1 = ld8(SH + 32 + aq);
      bf16x8 sl0 = ld8(SL + aq), sl1 = ld8(SL + 32 + aq);
      const float bom = bpf[L*64 + n0];
      #pragma unroll 1
      for (int mt = mt0; mt < mt1; ++mt) {
        const unsigned short* A0 = bG0 + ((mt*16 + arow) << 6);
        const unsigned short* A1 = bG1 + ((mt*16 + arow) << 6);
        const unsigned short* AR = bB0 + ((mt*16 + arow) << 6);
        bf16x8 g00 = ld8(A0 + aqs0), g01 = ld8(A0 + aqs1);
        bf16x8 g10 = ld8(A1 + aqs0), g11 = ld8(A1 + aqs1);
        bf16x8 r0 = ld8(AR + aqs0), r1 = ld8(AR + aqs1);
        f32x4 a0 = {0,0,0,0}, a1 = {0,0,0,0}, a2 = {0,0,0,0};
        a0 = MFMA(g00, c0h0, a0); a0 = MFMA(g00, c0l0, a0);
        a0 = MFMA(g01, c0h1, a0); a0 = MFMA(g01, c0l1, a0);
        a1 = MFMA(g10, c1h0, a1); a1 = MFMA(g10, c1l0, a1);
        a1 = MFMA(g11, c1h1, a1); a1 = MFMA(g11, c1l1, a1);
        a2 = MFMA(r0, sh0, a2); a2 = MFMA(r0, sl0, a2);
        a2 = MFMA(r1, sh1, a2); a2 = MFMA(r1, sl1, a2);
        const int rbase = mt*16 + rq;
        #pragma unroll
        for (int r = 0; r < 4; ++r) {
          int row = rbase + r;
          float v = a0[r] + a1[r] + a2[r] + bom;
          s_seq[row*64 + n0] = v;
          if (L == 3) s_xnb[(row << 6) + (n0 ^ ((rq7 + r) << 3))] = f2bf(v);
        }
      }
    }
    __syncthreads();
  }

  // ---------------- Attention tail ----------------
  // QKV: 96 units (K/V: 8 ct x 10 mt = 80; Q: 4 ct x 4 mt{0,2,5,7} = 16) over 8 waves = 12 each
  {
    #pragma unroll 1
    for (int i = 0; i < 12; ++i) {
      const int u = wv + 8*i;  // 0..95
      int j, mtk;
      if (u < 80) { j = 64 + (u & 7)*16 + arow; mtk = u >> 3; }
      else {
        int qi = u - 80;                 // 0..15
        j = (qi & 3)*16 + arow;
        int p = qi >> 2;                 // 0..3
        mtk = p*2 + (p >> 1);            // {0,2,5,7}
      }
      const unsigned short* Wh = wsb + AI_HI + j*64;
      const unsigned short* Wl = wsb + AI_LO + j*64;
      bf16x8 bh0 = ld8(Wh + aq), bh1 = ld8(Wh + 32 + aq);
      bf16x8 bl0 = ld8(Wl + aq), bl1 = ld8(Wl + 32 + aq);
      const float bj = aib[j];
      const unsigned short* A = s_xnb + ((mtk*16 + arow) << 6);
      bf16x8 ah0 = ld8(A + aqs0), ah1 = ld8(A + aqs1);
      f32x4 a0 = {0,0,0,0};
      a0 = MFMA(ah0, bh0, a0); a0 = MFMA(ah0, bl0, a0);
      a0 = MFMA(ah1, bh1, a0); a0 = MFMA(ah1, bl1, a0);
      const int rbase = mtk*16 + rq;
      #pragma unroll
      for (int r = 0; r < 4; ++r) {
        int row = rbase + r;
        int swr = (rq7 + r) << 3;
        float val = a0[r] + bj;
        if (u < 80) {
          if (j < 128) bB0[(row << 6) + ((j - 64) ^ swr)] = f2bf(val);   // K
          else         bB1[(row << 6) + ((j - 128) ^ swr)] = f2bf(val);  // V
        } else {
          if (row % 40 == 0) g0f[(row/40)*720 + 320 + j] = val;          // q per batch-row
        }
      }
    }
    if (tid < 256) g0f[(tid >> 6)*720 + 384 + (tid & 63)] = s_seq[(tid >> 6)*40*64 + (tid & 63)];
  }
  __syncthreads();

  // logits: 4 rows x 8 heads x 40 keys = 1280
  for (int e = tid; e < 1280; e += 512) {
    int br = e / 320, rem = e - br*320;
    int h = rem / 40, kk = rem - h*40;
    int row = br*40 + kk;
    int kbase = (row << 6) + ((h*8) ^ ((kk & 7) << 3));
    float acc = 0.f;
    #pragma unroll
    for (int i = 0; i < 8; ++i)
      acc += g0f[br*720 + 320 + h*8 + i] * bf2f(bB0[kbase + i]);
    g0f[br*720 + rem] = acc * 0.35355339059327373f;
  }
  __syncthreads();

  // softmax: 32 heads over 8 waves, 16 lanes per head (40 keys = 16+16+8)
  {
    const int hh = wv*4 + (lane >> 4), jl = lane & 15;
    float* pr = g0f + (hh >> 3)*720 + (hh & 7)*40;
    float a = pr[jl];
    float bv = pr[16 + jl];
    float cv = (jl < 8) ? pr[32 + jl] : -1e30f;
    float m = fmaxf(fmaxf(a, bv), cv);
    #pragma unroll
    for (int o = 8; o > 0; o >>= 1) m = fmaxf(m, __shfl_xor(m, o, 16));
    float pa = __expf(a - m), pb = __expf(bv - m), pc = (jl < 8) ? __expf(cv - m) : 0.f;
    float s = pa + pb + pc;
    #pragma unroll
    for (int o = 8; o > 0; o >>= 1) s += __shfl_xor(s, o, 16);
    float inv = 1.f / s;
    pr[jl] = pa * inv;
    pr[16 + jl] = pb * inv;
    if (jl < 8) pr[32 + jl] = pc * inv;
  }
  __syncthreads();

  // ao partials: 4 rows x 4 quarters x 64 d = 1024
  for (int e = tid; e < 1024; e += 512) {
    const int d = e & 63, qrt = (e >> 6) & 3, br = e >> 8, hh = d >> 3;
    float acc = 0.f;
    #pragma unroll
    for (int k = qrt*10; k < qrt*10 + 10; ++k) {
      int o = ((br*40 + k) << 6) + (d ^ ((k & 7) << 3));
      acc += g0f[br*720 + hh*40 + k] * bf2f(bB1[o]);
    }
    g1f[br*512 + qrt*64 + d] = acc;
  }
  __syncthreads();
  if (tid < 256) {
    float* p = g1f + (tid >> 6)*512;
    int d = tid & 63;
    p[256 + d] = p[d] + p[64 + d] + p[128 + d] + p[192 + d];
  }
  __syncthreads();

  // c = seq0 + ao @ aoW.T + aob
  if (tid < 256) {
    int br = tid >> 6, o = tid & 63;
    g0f[br*720 + 448 + o] = g0f[br*720 + 384 + o] + aob[o]
                          + dotg64(&g1f[br*512 + 256], aoW + (size_t)o*64);
  }
  __syncthreads();

  // MLP1: 4 rows x 128 = 512 exactly
  {
    int br = tid >> 7, o = tid & 127;
    g1f[br*512 + 320 + o] = fmaxf(b1[o] + dotg64(&g0f[br*720 + 448], w1 + (size_t)o*64), 0.f);
  }
  __syncthreads();

  // MLP2
  if (tid < 256) {
    int br = tid >> 6, o = tid & 63;
    float acc = dotg64(&g1f[br*512 + 320], w2 + (size_t)o*128)
              + dotg64(&g1f[br*512 + 384], w2 + (size_t)o*128 + 64);
    g1f[br*512 + 448 + o] = fmaxf(acc + b2[o], 0.f);
  }
  __syncthreads();

  if (tid < 256) {
    int br = tid >> 6;
    float v = g1f[br*512 + 448 + lane] * w3[lane];
    v = wred64(v);
    if (lane == 0) out[b*4 + br] = v + b3[0];
  }
}

extern "C" void kernel_launch(void* const* d_in, const int* in_sizes, int n_in,
                              void* d_out, int out_size, void* d_ws, size_t ws_size,
                              hipStream_t stream) {
  (void)n_in; (void)ws_size; (void)out_size;
  const float* dense_x = (const float*)d_in[0];
  const float* dense_W = (const float*)d_in[1];
  const float* dense_b = (const float*)d_in[2];
  const float* tbl     = (const float*)d_in[3];
  const float* cls     = (const float*)d_in[4];
  const float* ng      = (const float*)d_in[5];
  const float* nb      = (const float*)d_in[6];
  const float* xW      = (const float*)d_in[7];
  const float* xb      = (const float*)d_in[8];
  const float* Ap      = (const float*)d_in[9];
  const float* Dp      = (const float*)d_in[10];
  const float* oW      = (const float*)d_in[11];
  const float* ob      = (const float*)d_in[12];
  const float* mW      = (const float*)d_in[13];
  const float* mb      = (const float*)d_in[14];
  const float* aiW     = (const float*)d_in[15];
  const float* aib     = (const float*)d_in[16];
  const float* aoW     = (const float*)d_in[17];
  const float* aob     = (const float*)d_in[18];
  const float* w1      = (const float*)d_in[19];
  const float* b1      = (const float*)d_in[20];
  const float* w2      = (const float*)d_in[21];
  const float* b2      = (const float*)d_in[22];
  const float* w3      = (const float*)d_in[23];
  const float* b3      = (const float*)d_in[24];
  const int*   sidx    = (const int*)d_in[25];
  float* out = (float*)d_out;
  unsigned short* wsb = (unsigned short*)d_ws;

  hipLaunchKernelGGL(prep_kernel, dim3(256), dim3(256), 0, stream,
                     xW, oW, ob, mW, mb, aiW, Ap, wsb);

  const int B = in_sizes[0] / 13;  // 1024
  hipLaunchKernelGGL(Mamba4CTRV15_kernel, dim3(B/4), dim3(512), 0, stream,
                     dense_x, dense_W, dense_b, tbl, cls, ng, nb, xb, Dp, ob, mb,
                     aib, aoW, aob, w1, b1, w2, b2, w3, b3, sidx, wsb, out);
}

// Round 13
// 247.332 us; speedup vs baseline: 1.1058x; 1.0300x over previous
//
#include <hip/hip_runtime.h>

#define DEV static __device__ __forceinline__

typedef __attribute__((ext_vector_type(8))) short bf16x8;
typedef __attribute__((ext_vector_type(4))) float f32x4;

#define MFMA(a, b, c) __builtin_amdgcn_mfma_f32_16x16x32_bf16(a, b, c, 0, 0, 0)

DEV float bf2f(unsigned short h) { return __uint_as_float(((unsigned)h) << 16); }
DEV unsigned short f2bf(float f) {
  unsigned u = __float_as_uint(f);
  u += 0x7fffu + ((u >> 16) & 1u);
  return (unsigned short)(u >> 16);
}
DEV bf16x8 ld8(const unsigned short* p) { return *(const bf16x8*)p; }

DEV float dotg64(const float* x, const float* wrow) {
  const float4* wp = (const float4*)wrow;
  float a0 = 0.f, a1 = 0.f;
  #pragma unroll
  for (int c = 0; c < 8; ++c) {
    float4 u = wp[2*c], v = wp[2*c + 1];
    a0 = fmaf(u.x, x[8*c+0], a0); a0 = fmaf(u.y, x[8*c+1], a0);
    a0 = fmaf(u.z, x[8*c+2], a0); a0 = fmaf(u.w, x[8*c+3], a0);
    a1 = fmaf(v.x, x[8*c+4], a1); a1 = fmaf(v.y, x[8*c+5], a1);
    a1 = fmaf(v.z, x[8*c+6], a1); a1 = fmaf(v.w, x[8*c+7], a1);
  }
  return a0 + a1;
}
DEV float wred64(float v) {
  #pragma unroll
  for (int o = 32; o > 0; o >>= 1) v += __shfl_xor(v, o, 64);
  return v;
}

// d_ws layout (ushort element offsets): weights as bf16 hi/lo pairs.
// Fused composites: C0 = mW0@oW0, C1 = mW1@oW1, S = mW0+mW1 (hi/lo each),
// b' = mb + mW0@ob0 + mW1@ob1.
#define XW_HI 0        // 4*2*128*64 = 65536
#define XW_LO 65536
#define CW 131072      // per layer 24576: C0H,C0L,C1H,C1L,SH,SL (each 4096)
#define AI_HI 262144
#define AI_LO 274432
#define SC_OFF 286720  // f32: 8*256 gate-poly coefs
#define BP_OFF 290816  // f32: 4*64 fused bias b'

// bf16 tiles: 80 rows x 64 cols, stride 64, XOR swizzle:
// elem(row,d) = (row<<6) + (d ^ ((row&7)<<3)). 80 = 5x16 exact MFMA tiles.
// sw is a multiple of 8 -> u32/b64 accesses of adjacent d's stay legal.

__global__ void prep_kernel(const float* __restrict__ xW, const float* __restrict__ oW,
                            const float* __restrict__ ob, const float* __restrict__ mW,
                            const float* __restrict__ mb, const float* __restrict__ aiW,
                            const float* __restrict__ Ap, unsigned short* __restrict__ wsb) {
  const int gid = blockIdx.x * blockDim.x + threadIdx.x;
  const int stride = gridDim.x * blockDim.x;
  for (int i = gid; i < 65536; i += stride) {
    float x = xW[i]; unsigned short h = f2bf(x);
    wsb[XW_HI + i] = h; wsb[XW_LO + i] = f2bf(x - bf2f(h));
  }
  for (int i = gid; i < 32768; i += stride) {
    int L = i >> 13, rem = i & 8191;
    int dir = rem >> 12, n = (rem >> 6) & 63, d = rem & 63;
    const float* mrow = mW + L*8192 + n*128 + dir*64;
    const float* ocol = oW + L*8192 + dir*4096 + d;
    float acc = 0.f;
    #pragma unroll 8
    for (int j = 0; j < 64; ++j) acc = fmaf(mrow[j], ocol[j*64], acc);
    unsigned short h = f2bf(acc);
    int base = CW + L*24576 + dir*8192;
    wsb[base + n*64 + d] = h;
    wsb[base + 4096 + n*64 + d] = f2bf(acc - bf2f(h));
  }
  for (int i = gid; i < 16384; i += stride) {
    int L = i >> 12, n = (i >> 6) & 63, j = i & 63;
    float v = mW[L*8192 + n*128 + j] + mW[L*8192 + n*128 + 64 + j];
    unsigned short h = f2bf(v);
    int base = CW + L*24576 + 16384;
    wsb[base + n*64 + j] = h;
    wsb[base + 4096 + n*64 + j] = f2bf(v - bf2f(h));
  }
  {
    float* bp = (float*)(wsb + BP_OFF);
    for (int i = gid; i < 256; i += stride) {
      int L = i >> 6, n = i & 63;
      const float* mrow = mW + L*8192 + n*128;
      float acc = mb[L*64 + n];
      #pragma unroll 8
      for (int j = 0; j < 64; ++j) acc = fmaf(ob[(2*L)*64 + j], mrow[j], acc);
      #pragma unroll 8
      for (int j = 0; j < 64; ++j) acc = fmaf(ob[(2*L+1)*64 + j], mrow[64 + j], acc);
      bp[i] = acc;
    }
  }
  for (int i = gid; i < 12288; i += stride) {
    float x = aiW[i]; unsigned short h = f2bf(x);
    wsb[AI_HI + i] = h; wsb[AI_LO + i] = f2bf(x - bf2f(h));
  }
  float* sc = (float*)(wsb + SC_OFF);
  for (int i = gid; i < 512; i += stride) {
    int pi = i >> 6, d = i & 63;
    const float* a = Ap + (size_t)i * 16;
    float s1 = 0, s2 = 0, s3 = 0, s4 = 0;
    #pragma unroll
    for (int n = 0; n < 16; ++n) {
      float z = a[n]; float z2 = z * z;
      s1 += z; s2 += z2; s3 += z2 * z; s4 += z2 * z2;
    }
    sc[pi*256 + d]       = s1;
    sc[pi*256 + 64 + d]  = s2 * 0.5f;
    sc[pi*256 + 128 + d] = s3 * (1.f/6.f);
    sc[pi*256 + 192 + d] = s4 * (1.f/24.f);
  }
}

// R13 = R12 split into TWO INDEPENDENT 256-thread blocks per CU.
// R9-R12 eliminated: work (flat), forced ILP (neg), same-block TLP (neg),
// DS throughput (20% effective). Remaining idle (~60%) = barrier convergence
// + exposed LDS latency with LOCKSTEP waves: the 2 waves/SIMD are the same
// block and stall together at every barrier. Fix: same 2 waves/SIMD but from
// DIFFERENT blocks at different phases -> one block's stalls filled by the
// other's issue. 256-thr blocks provably co-reside (R3/R4); LDS 71,680 x2 =
// 143,360 <= 145,408 proven-fit. Per-wave work identical to R12 (10 xproj /
// 5 fused / 5 LN units, 40-step scan); 80 tokens = 5x16 exact, no pads.
// (256,2) bounds keep the 256-reg budget (no R3 spill trap).
// Falsifiers: occ ~11% -> no co-residency, revert; occ ~22% + flat dur ->
// per-wave latency chain is the wall, structure exhausted.
__global__ __launch_bounds__(256, 2)
void Mamba4CTRV16_kernel(
    const float* __restrict__ dense_x, const float* __restrict__ dense_W,
    const float* __restrict__ dense_b, const float* __restrict__ tbl,
    const float* __restrict__ cls, const float* __restrict__ ng,
    const float* __restrict__ nb, const float* __restrict__ xb,
    const float* __restrict__ Dp, const float* __restrict__ ob,
    const float* __restrict__ mb, const float* __restrict__ aib,
    const float* __restrict__ aoW, const float* __restrict__ aob,
    const float* __restrict__ w1, const float* __restrict__ b1,
    const float* __restrict__ w2, const float* __restrict__ b2,
    const float* __restrict__ w3, const float* __restrict__ b3,
    const int* __restrict__ sidx, const unsigned short* __restrict__ wsb,
    float* __restrict__ out) {
  __shared__ __align__(16) unsigned char smem[71680];
  float*          s_seq  = (float*)smem;                     // 80x64 f32 spine (20480)
  unsigned short* s_xnb  = (unsigned short*)(smem + 20480);  // 80x64 bf16 xn / final seq (10240)
  unsigned short* bG0    = (unsigned short*)(smem + 30720);  // gate0->scanout0 ; tail f32 g0f ; phase0 scratch
  unsigned short* bG1    = (unsigned short*)(smem + 40960);  // gate1->scanout1 ; tail f32 g1f
  unsigned short* bB0    = (unsigned short*)(smem + 51200);  // Bm0 -> residual bf16 (in-scan) ; tail: K
  unsigned short* bB1    = (unsigned short*)(smem + 61440);  // Bm1 ; tail: V
  float* g0f = (float*)bG0;          // tail: per-row 720 f32 {probs320, q64, seq0_64, c64} x2
  float* g1f = (float*)bG1;          // tail: per-row 512 f32 {aopart256, ao64, mlp1_128, mlp2_64} x2
  const float* scf = (const float*)(wsb + SC_OFF);
  const float* bpf = (const float*)(wsb + BP_OFF);

  const int tid = threadIdx.x, b = blockIdx.x;
  const int lane = tid & 63, wv = tid >> 6;  // wv 0..3
  const int arow = lane & 15;
  const int aq = (lane >> 4) * 8;
  const int rq = (lane >> 4) * 4;
  const int rq7 = rq & 7;
  const int swA = (arow & 7) << 3;
  const int aqs0 = aq ^ swA, aqs1 = (aq + 32) ^ swA;

  // ---------------- Phase 0: build seq for 2 rows ----------------
  {
    float* s_dx = g0f;                 // [0..13) row0, [16..29) row1
    int* s_idx = (int*)(g0f + 32);     // 52 ints
    if (tid < 13) s_dx[tid] = dense_x[(b*2)*13 + tid];
    else if (tid >= 16 && tid < 29) s_dx[tid] = dense_x[(b*2+1)*13 + (tid-16)];
    if (tid >= 64 && tid < 116) {
      int s = tid - 64, br = s / 26, si = s - br*26;
      int v = sidx[(b*2+br)*26 + si];
      v = v < 0 ? 0 : (v > 10000 ? 10000 : v);
      s_idx[s] = v;
    }
    __syncthreads();
    if (tid < 128) s_seq[(tid >> 6)*40*64 + (tid & 63)] = cls[tid & 63];
    {
      const int br = tid >> 7, j0 = tid & 127;
      float x[13];
      #pragma unroll
      for (int k = 0; k < 13; ++k) x[k] = s_dx[br*16 + k];
      for (int j = j0; j < 832; j += 128) {
        float acc = dense_b[j];
        #pragma unroll
        for (int k = 0; k < 13; ++k) acc = fmaf(x[k], dense_W[j*13 + k], acc);
        s_seq[(br*40 + 1 + (j >> 6))*64 + (j & 63)] = acc;
      }
    }
    for (int e = tid; e < 832; e += 256) {
      int br = e / 416, rem = e - br*416, s = rem >> 4, c = rem & 15;
      const float4* row = (const float4*)(tbl + ((size_t)(s*10001 + s_idx[br*26 + s]))*64);
      ((float4*)&s_seq[(br*40 + 14 + s)*64])[c] = row[c];
    }
  }
  __syncthreads();

  // ---------------- 4 bidirectional mamba layers ----------------
  for (int L = 0; L < 4; ++L) {
    const int pi0 = 2*L, pi1 = 2*L + 1;

    // LN 4-wide: 80 tokens = 5 sweeps x (4 waves x 4 token-groups);
    // lane = 4 adjacent d's (rotated per group to stagger banks).
    {
      const int g = lane >> 4, dl = lane & 15;
      const int dbase = 4 * ((dl + 4*g) & 15);
      const float4 ngv = *(const float4*)&ng[pi0*64 + dbase];
      const float4 nbv = *(const float4*)&nb[pi0*64 + dbase];
      #pragma unroll 1
      for (int sweep = 0; sweep < 5; ++sweep) {
        int t = sweep*16 + wv*4 + g;  // 0..79
        const float4 xv = *(const float4*)&s_seq[t*64 + dbase];
        float s = (xv.x + xv.y) + (xv.z + xv.w);
        float q = fmaf(xv.x, xv.x, fmaf(xv.y, xv.y, fmaf(xv.z, xv.z, xv.w*xv.w)));
        #pragma unroll
        for (int o = 8; o > 0; o >>= 1) { s += __shfl_xor(s, o, 64); q += __shfl_xor(q, o, 64); }
        float mean = s * (1.f/64.f);
        float var = q * (1.f/64.f) - mean*mean;
        float rs = rsqrtf(var + 1e-5f);
        unsigned short h0 = f2bf(fmaf((xv.x - mean)*rs, ngv.x, nbv.x));
        unsigned short h1 = f2bf(fmaf((xv.y - mean)*rs, ngv.y, nbv.y));
        unsigned short h2 = f2bf(fmaf((xv.z - mean)*rs, ngv.z, nbv.z));
        unsigned short h3 = f2bf(fmaf((xv.w - mean)*rs, ngv.w, nbv.w));
        int o2 = (t << 6) + (dbase ^ ((t & 7) << 3));
        unsigned lo = (unsigned)h0 | ((unsigned)h1 << 16);
        unsigned hi = (unsigned)h2 | ((unsigned)h3 << 16);
        *(uint2*)&s_xnb[o2] = make_uint2(lo, hi);
      }
    }
    __syncthreads();

    // xproj both dirs fused: 2 passes (cti): pass0 = delta cols (j 0..63),
    // pass1 = Bm cols (j 64..127); wave w -> col-tile (w + cti*4), 5 mt.
    {
      #pragma unroll 1
      for (int cti = 0; cti < 2; ++cti) {
        const int j = (wv + cti*4)*16 + arow;  // 0..127
        const unsigned short* Wh0 = wsb + XW_HI + pi0*8192 + j*64;
        const unsigned short* Wl0 = wsb + XW_LO + pi0*8192 + j*64;
        const unsigned short* Wh1 = wsb + XW_HI + pi1*8192 + j*64;
        const unsigned short* Wl1 = wsb + XW_LO + pi1*8192 + j*64;
        bf16x8 bh00 = ld8(Wh0 + aq), bh01 = ld8(Wh0 + 32 + aq);
        bf16x8 bl00 = ld8(Wl0 + aq), bl01 = ld8(Wl0 + 32 + aq);
        bf16x8 bh10 = ld8(Wh1 + aq), bh11 = ld8(Wh1 + 32 + aq);
        bf16x8 bl10 = ld8(Wl1 + aq), bl11 = ld8(Wl1 + 32 + aq);
        const float bj0 = xb[pi0*128 + j], bj1 = xb[pi1*128 + j];
        const bool isDelta = (cti == 0);  // uniform per pass
        float c10=0,c20=0,c30=0,c40=0,c11=0,c21=0,c31=0,c41=0;
        if (isDelta) {
          c10=scf[pi0*256+j]; c20=scf[pi0*256+64+j]; c30=scf[pi0*256+128+j]; c40=scf[pi0*256+192+j];
          c11=scf[pi1*256+j]; c21=scf[pi1*256+64+j]; c31=scf[pi1*256+128+j]; c41=scf[pi1*256+192+j];
        }
        #pragma unroll 1
        for (int mt = 0; mt < 5; ++mt) {
          const unsigned short* A = s_xnb + ((mt*16 + arow) << 6);
          bf16x8 ah0 = ld8(A + aqs0), ah1 = ld8(A + aqs1);
          f32x4 a0 = {0,0,0,0}, a1 = {0,0,0,0};
          a0 = MFMA(ah0, bh00, a0); a0 = MFMA(ah0, bl00, a0);
          a0 = MFMA(ah1, bh01, a0); a0 = MFMA(ah1, bl01, a0);
          a1 = MFMA(ah0, bh10, a1); a1 = MFMA(ah0, bl10, a1);
          a1 = MFMA(ah1, bh11, a1); a1 = MFMA(ah1, bl11, a1);
          const int rbase = mt*16 + rq;
          #pragma unroll
          for (int r = 0; r < 4; ++r) {
            int row = rbase + r;  // 0..79 exact
            int swr = (rq7 + r) << 3;
            float x0v = a0[r] + bj0, x1v = a1[r] + bj1;
            if (isDelta) {
              float sp0 = fmaxf(x0v, 0.f) + __logf(1.f + __expf(-fabsf(x0v)));
              float sp1 = fmaxf(x1v, 0.f) + __logf(1.f + __expf(-fabsf(x1v)));
              int o = (row << 6) + (j ^ swr);
              bG0[o] = f2bf(sp0 * fmaf(sp0, fmaf(sp0, fmaf(sp0, c40, c30), c20), c10));
              bG1[o] = f2bf(sp1 * fmaf(sp1, fmaf(sp1, fmaf(sp1, c41, c31), c21), c11));
            } else {
              int o = (row << 6) + ((j - 64) ^ swr);
              bB0[o] = f2bf(x0v);
              bB1[o] = f2bf(x1v);
            }
          }
        }
      }
    }
    __syncthreads();

    // Scan (paired): 128 streams of d-pairs (2 rows x 2 dirs x 32), 40 steps.
    // tid<64 -> dir0 (wave 0), 64..127 -> dir1 (wave 1): dir wave-uniform,
    // so the dir-0 residual overwrite of consumed Bm0 is a uniform branch.
    if (tid < 128) {
      const int d0 = (tid & 31) * 2, br = (tid >> 5) & 1, dir = tid >> 6;
      unsigned short* bmb = dir ? bB1 : bB0;
      unsigned short* gb = dir ? bG1 : bG0;
      const float2 dpd = *(const float2*)&Dp[(pi0 + dir)*64 + d0];
      const int base = br*40;
      float run0 = 0.f, run1 = 0.f;
      #pragma unroll
      for (int k = 0; k < 40; ++k) {
        int t = base + (dir ? (39 - k) : k);
        int o = (t << 6) + (d0 ^ ((t & 7) << 3));
        unsigned xn2 = *(const unsigned*)&s_xnb[o];
        unsigned bm2 = *(const unsigned*)&bmb[o];
        unsigned g2  = *(const unsigned*)&gb[o];
        float xn0 = bf2f((unsigned short)xn2), xn1 = bf2f((unsigned short)(xn2 >> 16));
        run0 = fmaf(xn0, bf2f((unsigned short)bm2), run0);
        run1 = fmaf(xn1, bf2f((unsigned short)(bm2 >> 16)), run1);
        float gate0 = 16.f + bf2f((unsigned short)g2);
        float gate1 = 16.f + bf2f((unsigned short)(g2 >> 16));
        unsigned short r0 = f2bf(fmaf(run0, gate0, xn0 * dpd.x));
        unsigned short r1 = f2bf(fmaf(run1, gate1, xn1 * dpd.y));
        *(unsigned*)&gb[o] = (unsigned)r0 | ((unsigned)r1 << 16);
        if (dir == 0) {
          float2 sv = *(const float2*)&s_seq[t*64 + d0];
          *(unsigned*)&bmb[o] = (unsigned)f2bf(sv.x) | ((unsigned)f2bf(sv.y) << 16);
        }
      }
    }
    __syncthreads();

    // FUSED out+merge: seq_new = g0@C0^T + g1@C1^T + res@S^T + b'
    // (res tile = bB0, written during scan). wave w -> col-tile w, 5 mt.
    {
      const int n0 = wv*16 + arow;  // 0..63
      const unsigned short* cbase = wsb + CW + L*24576;
      const unsigned short* C0H = cbase + n0*64;
      const unsigned short* C0L = cbase + 4096 + n0*64;
      const unsigned short* C1H = cbase + 8192 + n0*64;
      const unsigned short* C1L = cbase + 12288 + n0*64;
      const unsigned short* SH  = cbase + 16384 + n0*64;
      const unsigned short* SL  = cbase + 20480 + n0*64;
      bf16x8 c0h0 = ld8(C0H + aq), c0h1 = ld8(C0H + 32 + aq);
      bf16x8 c0l0 = ld8(C0L + aq), c0l1 = ld8(C0L + 32 + aq);
      bf16x8 c1h0 = ld8(C1H + aq), c1h1 = ld8(C1H + 32 + aq);
      bf16x8 c1l0 = ld8(C1L + aq), c1l1 = ld8(C1L + 32 + aq);
      bf16x8 sh0 = ld8(SH + aq), sh1 = ld8(SH + 32 + aq);
      bf16x8 sl0 = ld8(SL + aq), sl1 = ld8(SL + 32 + aq);
      const float bom = bpf[L*64 + n0];
      #pragma unroll 1
      for (int mt = 0; mt < 5; ++mt) {
        const unsigned short* A0 = bG0 + ((mt*16 + arow) << 6);
        const unsigned short* A1 = bG1 + ((mt*16 + arow) << 6);
        const unsigned short* AR = bB0 + ((mt*16 + arow) << 6);
        bf16x8 g00 = ld8(A0 + aqs0), g01 = ld8(A0 + aqs1);
        bf16x8 g10 = ld8(A1 + aqs0), g11 = ld8(A1 + aqs1);
        bf16x8 r0 = ld8(AR + aqs0), r1 = ld8(AR + aqs1);
        f32x4 a0 = {0,0,0,0}, a1 = {0,0,0,0}, a2 = {0,0,0,0};
        a0 = MFMA(g00, c0h0, a0); a0 = MFMA(g00, c0l0, a0);
        a0 = MFMA(g01, c0h1, a0); a0 = MFMA(g01, c0l1, a0);
        a1 = MFMA(g10, c1h0, a1); a1 = MFMA(g10, c1l0, a1);
        a1 = MFMA(g11, c1h1, a1); a1 = MFMA(g11, c1l1, a1);
        a2 = MFMA(r0, sh0, a2); a2 = MFMA(r0, sl0, a2);
        a2 = MFMA(r1, sh1, a2); a2 = MFMA(r1, sl1, a2);
        const int rbase = mt*16 + rq;
        #pragma unroll
        for (int r = 0; r < 4; ++r) {
          int row = rbase + r;
          float v = a0[r] + a1[r] + a2[r] + bom;
          s_seq[row*64 + n0] = v;
          if (L == 3) s_xnb[(row << 6) + (n0 ^ ((rq7 + r) << 3))] = f2bf(v);
        }
      }
    }
    __syncthreads();
  }

  // ---------------- Attention tail ----------------
  // QKV: 48 units (K/V: 8 ct x 5 mt = 40; Q: 4 ct x mt{0,2} = 8) over 4 waves = 12 each
  {
    #pragma unroll 1
    for (int i = 0; i < 12; ++i) {
      const int u = wv + 4*i;  // 0..47
      int j, mtk;
      if (u < 40) { j = 64 + (u & 7)*16 + arow; mtk = u >> 3; }
      else { int qi = u - 40; j = (qi & 3)*16 + arow; mtk = (qi >> 2) * 2; }
      const unsigned short* Wh = wsb + AI_HI + j*64;
      const unsigned short* Wl = wsb + AI_LO + j*64;
      bf16x8 bh0 = ld8(Wh + aq), bh1 = ld8(Wh + 32 + aq);
      bf16x8 bl0 = ld8(Wl + aq), bl1 = ld8(Wl + 32 + aq);
      const float bj = aib[j];
      const unsigned short* A = s_xnb + ((mtk*16 + arow) << 6);
      bf16x8 ah0 = ld8(A + aqs0), ah1 = ld8(A + aqs1);
      f32x4 a0 = {0,0,0,0};
      a0 = MFMA(ah0, bh0, a0); a0 = MFMA(ah0, bl0, a0);
      a0 = MFMA(ah1, bh1, a0); a0 = MFMA(ah1, bl1, a0);
      const int rbase = mtk*16 + rq;
      #pragma unroll
      for (int r = 0; r < 4; ++r) {
        int row = rbase + r;
        int swr = (rq7 + r) << 3;
        float val = a0[r] + bj;
        if (u < 40) {
          if (j < 128) bB0[(row << 6) + ((j - 64) ^ swr)] = f2bf(val);   // K
          else         bB1[(row << 6) + ((j - 128) ^ swr)] = f2bf(val);  // V
        } else {
          if (row == 0)       g0f[320 + j] = val;
          else if (row == 40) g0f[720 + 320 + j] = val;
        }
      }
    }
    if (tid < 128) g0f[(tid >> 6)*720 + 384 + (tid & 63)] = s_seq[(tid >> 6)*40*64 + (tid & 63)];
  }
  __syncthreads();

  // logits: 2 rows x 8 heads x 40 keys = 640
  for (int e = tid; e < 640; e += 256) {
    int br = e / 320, rem = e - br*320;
    int h = rem / 40, kk = rem - h*40;
    int row = br*40 + kk;
    int kbase = (row << 6) + ((h*8) ^ ((kk & 7) << 3));
    float acc = 0.f;
    #pragma unroll
    for (int i = 0; i < 8; ++i)
      acc += g0f[br*720 + 320 + h*8 + i] * bf2f(bB0[kbase + i]);
    g0f[br*720 + rem] = acc * 0.35355339059327373f;
  }
  __syncthreads();

  // softmax: 16 heads over 4 waves, 16 lanes per head (40 keys = 16+16+8)
  {
    const int hh = wv*4 + (lane >> 4), jl = lane & 15;
    float* pr = g0f + (hh >> 3)*720 + (hh & 7)*40;
    float a = pr[jl];
    float bv = pr[16 + jl];
    float cv = (jl < 8) ? pr[32 + jl] : -1e30f;
    float m = fmaxf(fmaxf(a, bv), cv);
    #pragma unroll
    for (int o = 8; o > 0; o >>= 1) m = fmaxf(m, __shfl_xor(m, o, 16));
    float pa = __expf(a - m), pb = __expf(bv - m), pc = (jl < 8) ? __expf(cv - m) : 0.f;
    float s = pa + pb + pc;
    #pragma unroll
    for (int o = 8; o > 0; o >>= 1) s += __shfl_xor(s, o, 16);
    float inv = 1.f / s;
    pr[jl] = pa * inv;
    pr[16 + jl] = pb * inv;
    if (jl < 8) pr[32 + jl] = pc * inv;
  }
  __syncthreads();

  // ao partials: 2 rows x 4 quarters x 64 d = 512
  for (int e = tid; e < 512; e += 256) {
    const int d = e & 63, qrt = (e >> 6) & 3, br = e >> 8, hh = d >> 3;
    float acc = 0.f;
    #pragma unroll
    for (int k = qrt*10; k < qrt*10 + 10; ++k) {
      int o = ((br*40 + k) << 6) + (d ^ ((k & 7) << 3));
      acc += g0f[br*720 + hh*40 + k] * bf2f(bB1[o]);
    }
    g1f[br*512 + qrt*64 + d] = acc;
  }
  __syncthreads();
  if (tid < 128) {
    float* p = g1f + (tid >> 6)*512;
    int d = tid & 63;
    p[256 + d] = p[d] + p[64 + d] + p[128 + d] + p[192 + d];
  }
  __syncthreads();

  // c = seq0 + ao @ aoW.T + aob
  if (tid < 128) {
    int br = tid >> 6, o = tid & 63;
    g0f[br*720 + 448 + o] = g0f[br*720 + 384 + o] + aob[o]
                          + dotg64(&g1f[br*512 + 256], aoW + (size_t)o*64);
  }
  __syncthreads();

  // MLP1: 2 rows x 128 = 256 exactly
  {
    int br = tid >> 7, o = tid & 127;
    g1f[br*512 + 320 + o] = fmaxf(b1[o] + dotg64(&g0f[br*720 + 448], w1 + (size_t)o*64), 0.f);
  }
  __syncthreads();

  // MLP2
  if (tid < 128) {
    int br = tid >> 6, o = tid & 63;
    float acc = dotg64(&g1f[br*512 + 320], w2 + (size_t)o*128)
              + dotg64(&g1f[br*512 + 384], w2 + (size_t)o*128 + 64);
    g1f[br*512 + 448 + o] = fmaxf(acc + b2[o], 0.f);
  }
  __syncthreads();

  if (tid < 128) {
    int br = tid >> 6;
    float v = g1f[br*512 + 448 + lane] * w3[lane];
    v = wred64(v);
    if (lane == 0) out[b*2 + br] = v + b3[0];
  }
}

extern "C" void kernel_launch(void* const* d_in, const int* in_sizes, int n_in,
                              void* d_out, int out_size, void* d_ws, size_t ws_size,
                              hipStream_t stream) {
  (void)n_in; (void)ws_size; (void)out_size;
  const float* dense_x = (const float*)d_in[0];
  const float* dense_W = (const float*)d_in[1];
  const float* dense_b = (const float*)d_in[2];
  const float* tbl     = (const float*)d_in[3];
  const float* cls     = (const float*)d_in[4];
  const float* ng      = (const float*)d_in[5];
  const float* nb      = (const float*)d_in[6];
  const float* xW      = (const float*)d_in[7];
  const float* xb      = (const float*)d_in[8];
  const float* Ap      = (const float*)d_in[9];
  const float* Dp      = (const float*)d_in[10];
  const float* oW      = (const float*)d_in[11];
  const float* ob      = (const float*)d_in[12];
  const float* mW      = (const float*)d_in[13];
  const float* mb      = (const float*)d_in[14];
  const float* aiW     = (const float*)d_in[15];
  const float* aib     = (const float*)d_in[16];
  const float* aoW     = (const float*)d_in[17];
  const float* aob     = (const float*)d_in[18];
  const float* w1      = (const float*)d_in[19];
  const float* b1      = (const float*)d_in[20];
  const float* w2      = (const float*)d_in[21];
  const float* b2      = (const float*)d_in[22];
  const float* w3      = (const float*)d_in[23];
  const float* b3      = (const float*)d_in[24];
  const int*   sidx    = (const int*)d_in[25];
  float* out = (float*)d_out;
  unsigned short* wsb = (unsigned short*)d_ws;

  hipLaunchKernelGGL(prep_kernel, dim3(256), dim3(256), 0, stream,
                     xW, oW, ob, mW, mb, aiW, Ap, wsb);

  const int B = in_sizes[0] / 13;  // 1024
  hipLaunchKernelGGL(Mamba4CTRV16_kernel, dim3(B/2), dim3(256), 0, stream,
                     dense_x, dense_W, dense_b, tbl, cls, ng, nb, xb, Dp, ob, mb,
                     aib, aoW, aob, w1, b1, w2, b2, w3, b3, sidx, wsb, out);
}